// Round 3
// baseline (767.694 us; speedup 1.0000x reference)
//
#include <hip/hip_runtime.h>
#include <stdint.h>

#define S 2048
#define D 64
#define NKT (S / 64)     // 32 key tiles of 64
#define SCALEF 0.125f    // 1/sqrt(64), folded into Q->f16 conversion (exact, pow2)

typedef __attribute__((ext_vector_type(8))) _Float16 half8;
typedef __attribute__((ext_vector_type(4))) float floatx4;
typedef __attribute__((ext_vector_type(4))) unsigned int uint32x4;

__device__ __forceinline__ float redsum16(float x) {
#pragma unroll
  for (int off = 8; off >= 1; off >>= 1) x += __shfl_xor(x, off, 16);
  return x;
}

// ---------------------------------------------------------------------------
// K [bh][key][d] f32 -> kh_tiled: 16B chunks, chunk = ((bh*32+kt)*512
//   + ch*256 + r*4 + quad), data[j] = K[bh][kt*64+r][ch*32+quad*8+j]  (f16x8)
// ---------------------------------------------------------------------------
__global__ __launch_bounds__(256) void conv_k_tiled(const float* __restrict__ k,
                                                    _Float16* __restrict__ kh) {
  __shared__ float tile[64][68];
  int bh = blockIdx.x >> 5;
  int kt = blockIdx.x & 31;
  const floatx4* src4 = (const floatx4*)(k + ((size_t)bh * S + (size_t)kt * 64) * D);
#pragma unroll
  for (int it = 0; it < 4; it++) {
    int idx = threadIdx.x + 256 * it;
    *(floatx4*)&tile[idx >> 4][(idx & 15) * 4] = src4[idx];
  }
  __syncthreads();
  half8* dst = (half8*)(kh + (size_t)(bh * 32 + kt) * 512 * 8);
#pragma unroll
  for (int it = 0; it < 2; it++) {
    int cl = threadIdx.x + 256 * it;
    int quad = cl & 3;
    int r = (cl >> 2) & 63;
    int ch = cl >> 8;
    const float* s = &tile[r][ch * 32 + quad * 8];
    half8 h;
#pragma unroll
    for (int j = 0; j < 8; j++) h[j] = (_Float16)s[j];
    dst[cl] = h;
  }
}

// ---------------------------------------------------------------------------
// V [bh][key][d] f32 -> vt_tiled: 16B chunks, chunk = ((bh*32+kt)*512
//   + c2*256 + d*4 + quad), data[j] = V[bh][kt*64 + c2*32+quad*8+j][d]
// ---------------------------------------------------------------------------
__global__ __launch_bounds__(256) void conv_v_tiled(const float* __restrict__ v,
                                                    _Float16* __restrict__ vt) {
  __shared__ float tile[64][68];
  int bh = blockIdx.x >> 5;
  int kt = blockIdx.x & 31;
  const floatx4* src4 = (const floatx4*)(v + ((size_t)bh * S + (size_t)kt * 64) * D);
#pragma unroll
  for (int it = 0; it < 4; it++) {
    int idx = threadIdx.x + 256 * it;
    *(floatx4*)&tile[idx >> 4][(idx & 15) * 4] = src4[idx];
  }
  __syncthreads();
  half8* dst = (half8*)(vt + (size_t)(bh * 32 + kt) * 512 * 8);
#pragma unroll
  for (int it = 0; it < 2; it++) {
    int cl = threadIdx.x + 256 * it;
    int quad = cl & 3;
    int d = (cl >> 2) & 63;
    int c2 = cl >> 8;
    int kb = c2 * 32 + quad * 8;
    half8 h;
#pragma unroll
    for (int j = 0; j < 8; j++) h[j] = (_Float16)tile[kb + j][d];
    dst[cl] = h;
  }
}

// ---------------------------------------------------------------------------
// mask [row][key] i32 -> uint32x4 at index (rt*32+kt)*64 + lane, component r4,
// byte nt = mask[rt*16 + (lane>>4)*4 + r4][kt*64 + nt*16 + (lane&15)]
// ---------------------------------------------------------------------------
__global__ __launch_bounds__(256) void pack_mask_kernel(const int* __restrict__ mask,
                                                        uint32_t* __restrict__ mp) {
  int i = blockIdx.x * 256 + threadIdx.x;
  int r4 = i & 3;
  int c16 = (i >> 2) & 15;
  int quad = (i >> 6) & 3;
  int kt = (i >> 8) & 31;
  int rt = i >> 13;
  int row = rt * 16 + quad * 4 + r4;
  const int* p = mask + (size_t)row * S + kt * 64 + c16;
  uint32_t b0 = (uint32_t)(p[0] != 0);
  uint32_t b1 = (uint32_t)(p[16] != 0);
  uint32_t b2 = (uint32_t)(p[32] != 0);
  uint32_t b3 = (uint32_t)(p[48] != 0);
  mp[i] = b0 | (b1 << 8) | (b2 << 16) | (b3 << 24);
}

// zero a float4-aligned buffer
__global__ __launch_bounds__(256) void zero_kernel(floatx4* __restrict__ p) {
  p[(size_t)blockIdx.x * 256 + threadIdx.x] = (floatx4){0.0f, 0.0f, 0.0f, 0.0f};
}

// ---------------------------------------------------------------------------
// Pass 1: partial softmax denominators over a 16-kt half-range.
// grid 2048 = (bh, qt, half); 8 blocks/CU -> 32 waves/CU (was 16).
// ---------------------------------------------------------------------------
__global__ __launch_bounds__(256, 8) void attn_pass1(
    const float* __restrict__ q, const _Float16* __restrict__ kh,
    const uint32_t* __restrict__ mp, float* __restrict__ l_ws) {
  const int half = blockIdx.x & 1;
  const int qt = (blockIdx.x >> 1) & 31;
  const int bh = blockIdx.x >> 6;
  const int lane = threadIdx.x & 63;
  const int wid = threadIdx.x >> 6;
  const int c16 = lane & 15;
  const int quad = lane >> 4;
  const int rowbase = qt * 64 + wid * 16;

  half8 aq[2];
  {
    const float* qrow = q + ((size_t)bh * S + rowbase + c16) * D + quad * 8;
#pragma unroll
    for (int ch = 0; ch < 2; ch++) {
      const floatx4* p4 = (const floatx4*)(qrow + ch * 32);
      floatx4 f0 = p4[0];
      floatx4 f1 = p4[1];
      half8 h;
      h[0] = (_Float16)(f0[0] * SCALEF); h[1] = (_Float16)(f0[1] * SCALEF);
      h[2] = (_Float16)(f0[2] * SCALEF); h[3] = (_Float16)(f0[3] * SCALEF);
      h[4] = (_Float16)(f1[0] * SCALEF); h[5] = (_Float16)(f1[1] * SCALEF);
      h[6] = (_Float16)(f1[2] * SCALEF); h[7] = (_Float16)(f1[3] * SCALEF);
      aq[ch] = h;
    }
  }

  const _Float16* kbase = kh + ((size_t)bh * 32 * 512 + (size_t)(c16 * 4 + quad)) * 8;
  const uint32x4* mb4 = (const uint32x4*)mp + (size_t)(qt * 4 + wid) * 32 * 64 + lane;

  float l_part[4];
#pragma unroll
  for (int r = 0; r < 4; r++) l_part[r] = 0.0f;

  const int kt0 = half * 16;
#pragma unroll 1
  for (int kt2 = 0; kt2 < 16; kt2++) {
    const int kt = kt0 + kt2;
    floatx4 acc[4];
#pragma unroll
    for (int nt = 0; nt < 4; nt++) {
      floatx4 a = {0.0f, 0.0f, 0.0f, 0.0f};
#pragma unroll
      for (int ch = 0; ch < 2; ch++) {
        half8 b = *(const half8*)(kbase + ((size_t)kt * 512 + ch * 256 + nt * 64) * 8);
        a = __builtin_amdgcn_mfma_f32_16x16x32_f16(aq[ch], b, a, 0, 0, 0);
      }
      acc[nt] = a;
    }
    uint32x4 mm = mb4[(size_t)kt * 64];
#pragma unroll
    for (int r = 0; r < 4; r++) {
      uint32_t mb = mm[r];
#pragma unroll
      for (int nt = 0; nt < 4; nt++) {
        float p = ((mb >> (8 * nt)) & 1u) ? __expf(acc[nt][r]) : 0.0f;
        l_part[r] += p;
      }
    }
  }

#pragma unroll
  for (int r = 0; r < 4; r++) {
    float s = redsum16(l_part[r]);
    if (c16 == 0)
      atomicAdd(&l_ws[(size_t)bh * S + rowbase + 4 * quad + r], s);
  }
}

// ---------------------------------------------------------------------------
// Pass 2: recompute S over the half-range, write attn, partial O via atomics.
// ---------------------------------------------------------------------------
__global__ __launch_bounds__(256, 8) void attn_pass2(
    const float* __restrict__ q, const _Float16* __restrict__ kh,
    const _Float16* __restrict__ vt, const uint32_t* __restrict__ mp,
    const float* __restrict__ l_ws, float* __restrict__ out_o,
    float* __restrict__ out_attn) {
  const int half = blockIdx.x & 1;
  const int qt = (blockIdx.x >> 1) & 31;
  const int bh = blockIdx.x >> 6;
  const int lane = threadIdx.x & 63;
  const int wid = threadIdx.x >> 6;
  const int c16 = lane & 15;
  const int quad = lane >> 4;
  const int rowbase = qt * 64 + wid * 16;

  half8 aq[2];
  {
    const float* qrow = q + ((size_t)bh * S + rowbase + c16) * D + quad * 8;
#pragma unroll
    for (int ch = 0; ch < 2; ch++) {
      const floatx4* p4 = (const floatx4*)(qrow + ch * 32);
      floatx4 f0 = p4[0];
      floatx4 f1 = p4[1];
      half8 h;
      h[0] = (_Float16)(f0[0] * SCALEF); h[1] = (_Float16)(f0[1] * SCALEF);
      h[2] = (_Float16)(f0[2] * SCALEF); h[3] = (_Float16)(f0[3] * SCALEF);
      h[4] = (_Float16)(f1[0] * SCALEF); h[5] = (_Float16)(f1[1] * SCALEF);
      h[6] = (_Float16)(f1[2] * SCALEF); h[7] = (_Float16)(f1[3] * SCALEF);
      aq[ch] = h;
    }
  }

  const _Float16* kbase = kh + ((size_t)bh * 32 * 512 + (size_t)(c16 * 4 + quad)) * 8;
  const _Float16* vbase = vt + ((size_t)bh * 32 * 512 + (size_t)(c16 * 4 + quad)) * 8;
  const uint32x4* mb4 = (const uint32x4*)mp + (size_t)(qt * 4 + wid) * 32 * 64 + lane;

  // denominators (total over both halves, pass 1 already completed)
  float inv_l[4];
#pragma unroll
  for (int r = 0; r < 4; r++)
    inv_l[r] = 1.0f / l_ws[(size_t)bh * S + rowbase + 4 * quad + r];

  __shared__ __align__(16) _Float16 plds[2][4][16][72];
  floatx4 oacc[4];
#pragma unroll
  for (int nt = 0; nt < 4; nt++) oacc[nt] = (floatx4){0.0f, 0.0f, 0.0f, 0.0f};

  float* attn_base = out_attn + ((size_t)bh * S + rowbase + 4 * quad) * S + c16;

  const int kt0 = half * 16;
#pragma unroll 1
  for (int kt2 = 0; kt2 < 16; kt2++) {
    const int kt = kt0 + kt2;
    floatx4 acc[4];
#pragma unroll
    for (int nt = 0; nt < 4; nt++) {
      floatx4 a = {0.0f, 0.0f, 0.0f, 0.0f};
#pragma unroll
      for (int ch = 0; ch < 2; ch++) {
        half8 b = *(const half8*)(kbase + ((size_t)kt * 512 + ch * 256 + nt * 64) * 8);
        a = __builtin_amdgcn_mfma_f32_16x16x32_f16(aq[ch], b, a, 0, 0, 0);
      }
      acc[nt] = a;
    }
    uint32x4 mm = mb4[(size_t)kt * 64];
    _Float16 (*pb)[72] = plds[kt2 & 1][wid];
#pragma unroll
    for (int r = 0; r < 4; r++) {
      uint32_t mb = mm[r];
#pragma unroll
      for (int nt = 0; nt < 4; nt++) {
        float p = ((mb >> (8 * nt)) & 1u) ? __expf(acc[nt][r]) : 0.0f;
        float av = p * inv_l[r];
        __builtin_nontemporal_store(av, &attn_base[(size_t)r * S + kt * 64 + nt * 16]);
        pb[4 * quad + r][nt * 16 + c16] = (_Float16)av;
      }
    }
    __asm__ volatile("s_waitcnt lgkmcnt(0)" ::: "memory");
    half8 a2[2];
#pragma unroll
    for (int c2 = 0; c2 < 2; c2++)
      a2[c2] = *(const half8*)&pb[c16][c2 * 32 + quad * 8];
#pragma unroll
    for (int nt = 0; nt < 4; nt++) {
      floatx4 o = oacc[nt];
#pragma unroll
      for (int c2 = 0; c2 < 2; c2++) {
        half8 b2 = *(const half8*)(vbase + ((size_t)kt * 512 + c2 * 256 + nt * 64) * 8);
        o = __builtin_amdgcn_mfma_f32_16x16x32_f16(a2[c2], b2, o, 0, 0, 0);
      }
      oacc[nt] = o;
    }
  }

  // O partial: exactly 2 atomic f32 adds per element onto zeroed base
  // (2 contributions, commutative -> bit-deterministic)
  float* obase = out_o + ((size_t)bh * S + rowbase + 4 * quad) * D + c16;
#pragma unroll
  for (int nt = 0; nt < 4; nt++)
#pragma unroll
    for (int r = 0; r < 4; r++)
      atomicAdd(&obase[(size_t)r * D + nt * 16], oacc[nt][r]);
}

extern "C" void kernel_launch(void* const* d_in, const int* in_sizes, int n_in,
                              void* d_out, int out_size, void* d_ws, size_t ws_size,
                              hipStream_t stream) {
  const float* q = (const float*)d_in[0];
  const float* k = (const float*)d_in[1];
  const float* v = (const float*)d_in[2];
  const int* mask = (const int*)d_in[3];

  char* ws = (char*)d_ws;
  _Float16* kh = (_Float16*)ws;               // 8,388,608 B (tiled)
  _Float16* vt = (_Float16*)(ws + 8388608);   // 8,388,608 B (tiled)
  uint32_t* mp = (uint32_t*)(ws + 16777216);  // 4,194,304 B
  float* l_ws = (float*)(ws + 20971520);      //   262,144 B (total 21.25 MiB)

  float* out_o = (float*)d_out;                       // [2,16,2048,64]
  float* out_attn = out_o + (size_t)32 * S * D;       // [2,16,2048,2048]

  conv_k_tiled<<<1024, 256, 0, stream>>>(k, kh);
  conv_v_tiled<<<1024, 256, 0, stream>>>(v, vt);
  pack_mask_kernel<<<4096, 256, 0, stream>>>(mask, mp);
  zero_kernel<<<64, 256, 0, stream>>>((floatx4*)l_ws);         // 64K floats
  zero_kernel<<<16384, 256, 0, stream>>>((floatx4*)out_o);     // 16.8M floats
  attn_pass1<<<2048, 256, 0, stream>>>(q, kh, mp, l_ws);
  attn_pass2<<<2048, 256, 0, stream>>>(q, kh, vt, mp, l_ws, out_o, out_attn);
}

// Round 4
// 693.546 us; speedup vs baseline: 1.1069x; 1.1069x over previous
//
#include <hip/hip_runtime.h>
#include <stdint.h>

#define S 2048
#define D 64
#define NKT (S / 64)     // 32 key tiles of 64
#define SCALEF 0.125f    // 1/sqrt(64), folded into Q->f16 conversion (exact, pow2)

typedef __attribute__((ext_vector_type(8))) _Float16 half8;
typedef __attribute__((ext_vector_type(4))) float floatx4;
typedef __attribute__((ext_vector_type(4))) unsigned int uint32x4;

__device__ __forceinline__ float redsum16(float x) {
#pragma unroll
  for (int off = 8; off >= 1; off >>= 1) x += __shfl_xor(x, off, 16);
  return x;
}

// ---------------------------------------------------------------------------
// K [bh][key][d] f32 -> kh_tiled: 16B chunks, chunk = ((bh*32+kt)*512
//   + ch*256 + r*4 + quad), data[j] = K[bh][kt*64+r][ch*32+quad*8+j]  (f16x8)
// ---------------------------------------------------------------------------
__global__ __launch_bounds__(256) void conv_k_tiled(const float* __restrict__ k,
                                                    _Float16* __restrict__ kh) {
  __shared__ float tile[64][68];
  int bh = blockIdx.x >> 5;
  int kt = blockIdx.x & 31;
  const floatx4* src4 = (const floatx4*)(k + ((size_t)bh * S + (size_t)kt * 64) * D);
#pragma unroll
  for (int it = 0; it < 4; it++) {
    int idx = threadIdx.x + 256 * it;
    *(floatx4*)&tile[idx >> 4][(idx & 15) * 4] = src4[idx];
  }
  __syncthreads();
  half8* dst = (half8*)(kh + (size_t)(bh * 32 + kt) * 512 * 8);
#pragma unroll
  for (int it = 0; it < 2; it++) {
    int cl = threadIdx.x + 256 * it;
    int quad = cl & 3;
    int r = (cl >> 2) & 63;
    int ch = cl >> 8;
    const float* s = &tile[r][ch * 32 + quad * 8];
    half8 h;
#pragma unroll
    for (int j = 0; j < 8; j++) h[j] = (_Float16)s[j];
    dst[cl] = h;
  }
}

// ---------------------------------------------------------------------------
// V [bh][key][d] f32 -> vt_tiled: 16B chunks, chunk = ((bh*32+kt)*512
//   + c2*256 + d*4 + quad), data[j] = V[bh][kt*64 + c2*32+quad*8+j][d]
// ---------------------------------------------------------------------------
__global__ __launch_bounds__(256) void conv_v_tiled(const float* __restrict__ v,
                                                    _Float16* __restrict__ vt) {
  __shared__ float tile[64][68];
  int bh = blockIdx.x >> 5;
  int kt = blockIdx.x & 31;
  const floatx4* src4 = (const floatx4*)(v + ((size_t)bh * S + (size_t)kt * 64) * D);
#pragma unroll
  for (int it = 0; it < 4; it++) {
    int idx = threadIdx.x + 256 * it;
    *(floatx4*)&tile[idx >> 4][(idx & 15) * 4] = src4[idx];
  }
  __syncthreads();
  half8* dst = (half8*)(vt + (size_t)(bh * 32 + kt) * 512 * 8);
#pragma unroll
  for (int it = 0; it < 2; it++) {
    int cl = threadIdx.x + 256 * it;
    int quad = cl & 3;
    int d = (cl >> 2) & 63;
    int c2 = cl >> 8;
    int kb = c2 * 32 + quad * 8;
    half8 h;
#pragma unroll
    for (int j = 0; j < 8; j++) h[j] = (_Float16)tile[kb + j][d];
    dst[cl] = h;
  }
}

// ---------------------------------------------------------------------------
// mask [row][key] i32 -> uint32x4 at index (rt*32+kt)*64 + lane, component r4,
// byte nt = mask[rt*16 + (lane>>4)*4 + r4][kt*64 + nt*16 + (lane&15)]
// ---------------------------------------------------------------------------
__global__ __launch_bounds__(256) void pack_mask_kernel(const int* __restrict__ mask,
                                                        uint32_t* __restrict__ mp) {
  int i = blockIdx.x * 256 + threadIdx.x;
  int r4 = i & 3;
  int c16 = (i >> 2) & 15;
  int quad = (i >> 6) & 3;
  int kt = (i >> 8) & 31;
  int rt = i >> 13;
  int row = rt * 16 + quad * 4 + r4;
  const int* p = mask + (size_t)row * S + kt * 64 + c16;
  uint32_t b0 = (uint32_t)(p[0] != 0);
  uint32_t b1 = (uint32_t)(p[16] != 0);
  uint32_t b2 = (uint32_t)(p[32] != 0);
  uint32_t b3 = (uint32_t)(p[48] != 0);
  mp[i] = b0 | (b1 << 8) | (b2 << 16) | (b3 << 24);
}

// ---------------------------------------------------------------------------
// Fused attention. Block = 256 thr = 4 waves; each wave owns 16 q-rows.
// XCD swizzle: all 32 q-tiles of a bh land on one XCD (bid%8 round-robin),
// keeping that bh's K/V/mask (1.1 MB) resident in the XCD's 4MB L2.
// P tile staged in LDS as f32: feeds both 4x dwordx4 attn stores (was 16
// scalar stores) and the PV MFMA A-fragment (ds_read_b128 + cvt).
// ---------------------------------------------------------------------------
__global__ __launch_bounds__(256, 4) void attn_kernel(
    const float* __restrict__ q, const _Float16* __restrict__ kh,
    const _Float16* __restrict__ vt, const uint32_t* __restrict__ mp,
    float* __restrict__ out_o, float* __restrict__ out_attn) {
  const int bid = blockIdx.x;
  const int qt = (bid >> 3) & 31;
  const int bh = (bid & 7) + 8 * (bid >> 8);
  const int lane = threadIdx.x & 63;
  const int wid = threadIdx.x >> 6;
  const int c16 = lane & 15;
  const int quad = lane >> 4;
  const int rowbase = qt * 64 + wid * 16;

  // Q fragments (A-operand), resident, pre-scaled by 1/sqrt(d):
  half8 aq[2];
  {
    const float* qrow = q + ((size_t)bh * S + rowbase + c16) * D + quad * 8;
#pragma unroll
    for (int ch = 0; ch < 2; ch++) {
      const floatx4* p4 = (const floatx4*)(qrow + ch * 32);
      floatx4 f0 = p4[0];
      floatx4 f1 = p4[1];
      half8 h;
      h[0] = (_Float16)(f0[0] * SCALEF); h[1] = (_Float16)(f0[1] * SCALEF);
      h[2] = (_Float16)(f0[2] * SCALEF); h[3] = (_Float16)(f0[3] * SCALEF);
      h[4] = (_Float16)(f1[0] * SCALEF); h[5] = (_Float16)(f1[1] * SCALEF);
      h[6] = (_Float16)(f1[2] * SCALEF); h[7] = (_Float16)(f1[3] * SCALEF);
      aq[ch] = h;
    }
  }

  const _Float16* kbase = kh + ((size_t)bh * 32 * 512 + (size_t)(c16 * 4 + quad)) * 8;
  const _Float16* vbase = vt + ((size_t)bh * 32 * 512 + (size_t)(c16 * 4 + quad)) * 8;
  const uint32x4* mb4 = (const uint32x4*)mp + (size_t)(qt * 4 + wid) * 32 * 64 + lane;

  // ---------- pass 1: per-lane partial denominators ----------
  float l_part[4];
#pragma unroll
  for (int r = 0; r < 4; r++) l_part[r] = 0.0f;

#pragma unroll 1
  for (int kt = 0; kt < NKT; kt++) {
    floatx4 acc[4];
    __builtin_amdgcn_s_setprio(1);
#pragma unroll
    for (int nt = 0; nt < 4; nt++) {
      floatx4 a = {0.0f, 0.0f, 0.0f, 0.0f};
#pragma unroll
      for (int ch = 0; ch < 2; ch++) {
        half8 b = *(const half8*)(kbase + ((size_t)kt * 512 + ch * 256 + nt * 64) * 8);
        a = __builtin_amdgcn_mfma_f32_16x16x32_f16(aq[ch], b, a, 0, 0, 0);
      }
      acc[nt] = a;
    }
    __builtin_amdgcn_s_setprio(0);
    uint32x4 mm = mb4[(size_t)kt * 64];
#pragma unroll
    for (int r = 0; r < 4; r++) {
      uint32_t mb = mm[r];
#pragma unroll
      for (int nt = 0; nt < 4; nt++) {
        float p = ((mb >> (8 * nt)) & 1u) ? __expf(acc[nt][r]) : 0.0f;
        l_part[r] += p;
      }
    }
  }

  float inv_l[4];
#pragma unroll
  for (int r = 0; r < 4; r++) inv_l[r] = 1.0f / redsum16(l_part[r]);

  // ---------- pass 2: recompute S, stage P (f32) in LDS, wide attn stores, PV ----------
  __shared__ __align__(16) float sst[2][4][16][68];  // double-buffered per-wave P tile (f32)
  floatx4 oacc[4];
#pragma unroll
  for (int nt = 0; nt < 4; nt++) oacc[nt] = (floatx4){0.0f, 0.0f, 0.0f, 0.0f};

  const int srow = lane >> 4;        // store-phase row-within-group
  const int scol = (lane & 15) * 4;  // store-phase col (f32 units)
  float* attn_srow_base = out_attn + ((size_t)bh * S + rowbase) * S;

#pragma unroll 1
  for (int kt = 0; kt < NKT; kt++) {
    floatx4 acc[4];
    __builtin_amdgcn_s_setprio(1);
#pragma unroll
    for (int nt = 0; nt < 4; nt++) {
      floatx4 a = {0.0f, 0.0f, 0.0f, 0.0f};
#pragma unroll
      for (int ch = 0; ch < 2; ch++) {
        half8 b = *(const half8*)(kbase + ((size_t)kt * 512 + ch * 256 + nt * 64) * 8);
        a = __builtin_amdgcn_mfma_f32_16x16x32_f16(aq[ch], b, a, 0, 0, 0);
      }
      acc[nt] = a;
    }
    __builtin_amdgcn_s_setprio(0);
    uint32x4 mm = mb4[(size_t)kt * 64];
    float (*sb)[68] = sst[kt & 1][wid];
#pragma unroll
    for (int r = 0; r < 4; r++) {
      uint32_t mb = mm[r];
#pragma unroll
      for (int nt = 0; nt < 4; nt++) {
        float p = ((mb >> (8 * nt)) & 1u) ? __expf(acc[nt][r]) : 0.0f;
        sb[4 * quad + r][nt * 16 + c16] = p * inv_l[r];
      }
    }
    // wave-internal LDS drain: writes done before cross-lane reads
    __asm__ volatile("s_waitcnt lgkmcnt(0)" ::: "memory");
    // wide attn stores: 4 x dwordx4, each instr = 4 rows x 256B contiguous
#pragma unroll
    for (int g = 0; g < 4; g++) {
      floatx4 vv = *(const floatx4*)&sb[g * 4 + srow][scol];
      __builtin_nontemporal_store(
          vv, (floatx4*)(attn_srow_base + (size_t)(g * 4 + srow) * S + kt * 64 + scol));
    }
    // PV A-fragment from f32 tile (ds_read_b128 x4 + cvt)
    half8 a2[2];
#pragma unroll
    for (int c2 = 0; c2 < 2; c2++) {
      floatx4 lo = *(const floatx4*)&sb[c16][c2 * 32 + quad * 8];
      floatx4 hi = *(const floatx4*)&sb[c16][c2 * 32 + quad * 8 + 4];
      half8 h;
      h[0] = (_Float16)lo[0]; h[1] = (_Float16)lo[1];
      h[2] = (_Float16)lo[2]; h[3] = (_Float16)lo[3];
      h[4] = (_Float16)hi[0]; h[5] = (_Float16)hi[1];
      h[6] = (_Float16)hi[2]; h[7] = (_Float16)hi[3];
      a2[c2] = h;
    }
    __builtin_amdgcn_s_setprio(1);
#pragma unroll
    for (int nt = 0; nt < 4; nt++) {  // nt tiles the d dimension of O
      floatx4 o = oacc[nt];
#pragma unroll
      for (int c2 = 0; c2 < 2; c2++) {
        half8 b2 = *(const half8*)(vbase + ((size_t)kt * 512 + c2 * 256 + nt * 64) * 8);
        o = __builtin_amdgcn_mfma_f32_16x16x32_f16(a2[c2], b2, o, 0, 0, 0);
      }
      oacc[nt] = o;
    }
    __builtin_amdgcn_s_setprio(0);
    // no trailing WAR wait: next iteration writes the other sst buffer
  }

  // write O (C-layout: row=4*quad+r, col=d=nt*16+c16), nontemporal
  float* obase = out_o + ((size_t)bh * S + rowbase + 4 * quad) * D + c16;
#pragma unroll
  for (int nt = 0; nt < 4; nt++)
#pragma unroll
    for (int r = 0; r < 4; r++)
      __builtin_nontemporal_store(oacc[nt][r], &obase[(size_t)r * D + nt * 16]);
}

extern "C" void kernel_launch(void* const* d_in, const int* in_sizes, int n_in,
                              void* d_out, int out_size, void* d_ws, size_t ws_size,
                              hipStream_t stream) {
  const float* q = (const float*)d_in[0];
  const float* k = (const float*)d_in[1];
  const float* v = (const float*)d_in[2];
  const int* mask = (const int*)d_in[3];

  char* ws = (char*)d_ws;
  _Float16* kh = (_Float16*)ws;               // 8,388,608 B (tiled)
  _Float16* vt = (_Float16*)(ws + 8388608);   // 8,388,608 B (tiled)
  uint32_t* mp = (uint32_t*)(ws + 16777216);  // 4,194,304 B  (total 20 MiB)

  float* out_o = (float*)d_out;                       // [2,16,2048,64]
  float* out_attn = out_o + (size_t)32 * S * D;       // [2,16,2048,2048]

  conv_k_tiled<<<1024, 256, 0, stream>>>(k, kh);
  conv_v_tiled<<<1024, 256, 0, stream>>>(v, vt);
  pack_mask_kernel<<<4096, 256, 0, stream>>>(mask, mp);
  attn_kernel<<<1024, 256, 0, stream>>>(q, kh, vt, mp, out_o, out_attn);
}